// Round 7
// baseline (367.484 us; speedup 1.0000x reference)
//
#include <hip/hip_runtime.h>

#define N_NODES   150000
#define N_EDGES   3000000
#define EMBED_DIM 64
#define N_UNITS   (N_EDGES / 4)                         // 750000 int4 units
#define NREG      2344                                  // regions of 64 nodes
#define CHUNK_U   2048                                  // int4 units per chunk
#define CHUNK_E   (CHUNK_U * 4)                         // 8192 edges per chunk
#define NCB       ((N_UNITS + CHUNK_U - 1) / CHUNK_U)   // 367 chunks
#define REC_MAX   2560                                  // region staging (avg 1280, +30σ margin)

typedef unsigned int uint;

// ---- bf16 helpers (RNE pack, shift unpack) ----
__device__ inline uint pack2_bf16(float a, float b) {
    uint ua = __float_as_uint(a);
    uint ub = __float_as_uint(b);
    ua += 0x7fffu + ((ua >> 16) & 1u);
    ub += 0x7fffu + ((ub >> 16) & 1u);
    return (ua >> 16) | (ub & 0xffff0000u);
}
#define FMA2(u, A0, A1)                                        \
    {   float _lo = __uint_as_float((u) << 16);                \
        float _hi = __uint_as_float((u) & 0xffff0000u);        \
        (A0) += w * _lo;  (A1) += w * _hi; }

// ---------- fp32 -> bf16 convert ----------
__global__ void k_to_bf16(const float4* __restrict__ in, uint2* __restrict__ out, int n4) {
    int i = blockIdx.x * blockDim.x + threadIdx.x;
    if (i < n4) {
        float4 v = in[i];
        out[i] = make_uint2(pack2_bf16(v.x, v.y), pack2_bf16(v.z, v.w));
    }
}

// ---------- 1. per-chunk region histogram + in-LDS exclusive scan ----------
// bh[k][b] = exclusive offset of region b within chunk k's bkt segment.
// rowtot[k] = edges in chunk k.
__global__ __launch_bounds__(256) void k_count(const int4* __restrict__ dst4,
                                               uint* __restrict__ bh,
                                               uint* __restrict__ rowtot) {
    __shared__ uint cnt[NREG];
    __shared__ uint part[256];
    int t = threadIdx.x;
    for (int b = t; b < NREG; b += 256) cnt[b] = 0;
    __syncthreads();
    int base = blockIdx.x * CHUNK_U;
    for (int i = t; i < CHUNK_U; i += 256) {
        int u = base + i;
        if (u < N_UNITS) {
            int4 d = dst4[u];
            atomicAdd(&cnt[d.x >> 6], 1u);
            atomicAdd(&cnt[d.y >> 6], 1u);
            atomicAdd(&cnt[d.z >> 6], 1u);
            atomicAdd(&cnt[d.w >> 6], 1u);
        }
    }
    __syncthreads();
    // exclusive scan of cnt[0..NREG) in place
    const int CPT = (NREG + 255) / 256;     // 10
    int b0 = t * CPT, b1 = b0 + CPT; if (b1 > NREG) b1 = NREG; if (b0 > NREG) b0 = NREG;
    uint own = 0;
    for (int b = b0; b < b1; ++b) own += cnt[b];
    part[t] = own;
    __syncthreads();
    for (int off = 1; off < 256; off <<= 1) {
        uint v = (t >= off) ? part[t - off] : 0;
        __syncthreads();
        part[t] += v;
        __syncthreads();
    }
    uint run = part[t] - own;
    for (int b = b0; b < b1; ++b) { uint c = cnt[b]; cnt[b] = run; run += c; }
    __syncthreads();
    for (int b = t; b < NREG; b += 256) bh[blockIdx.x * NREG + b] = cnt[b];
    if (t == 255) rowtot[blockIdx.x] = part[255];
}

// ---------- 2. region totals from scanned offsets (diff trick) ----------
__global__ void k_cols(const uint* __restrict__ bh, const uint* __restrict__ rowtot,
                       uint* __restrict__ tot) {
    int r = blockIdx.x * blockDim.x + threadIdx.x;
    if (r >= NREG) return;
    uint run = 0;
    if (r + 1 < NREG) {
        for (int k = 0; k < NCB; ++k)
            run += bh[k * NREG + r + 1] - bh[k * NREG + r];
    } else {
        for (int k = 0; k < NCB; ++k)
            run += rowtot[k] - bh[k * NREG + r];
    }
    tot[r] = run;
}

// ---------- 3. exclusive scan of 2344 region totals -> binPtr[0..NREG] ----------
__global__ void k_scan_small(const uint* __restrict__ tot, int* __restrict__ binPtr) {
    __shared__ uint s[1024];
    int t = threadIdx.x;
    int base = t * 3;
    uint v0 = (base + 0 < NREG) ? tot[base + 0] : 0;
    uint v1 = (base + 1 < NREG) ? tot[base + 1] : 0;
    uint v2 = (base + 2 < NREG) ? tot[base + 2] : 0;
    uint s3 = v0 + v1 + v2;
    s[t] = s3;
    __syncthreads();
    for (int off = 1; off < 1024; off <<= 1) {
        uint add = (t >= off) ? s[t - off] : 0;
        __syncthreads();
        s[t] += add;
        __syncthreads();
    }
    uint excl = s[t] - s3;
    if (base + 0 < NREG) binPtr[base + 0] = (int)excl;
    if (base + 1 < NREG) binPtr[base + 1] = (int)(excl + v0);
    if (base + 2 < NREG) binPtr[base + 2] = (int)(excl + v0 + v1);
    if (t == 1023) binPtr[NREG] = (int)s[1023];
}

// ---------- 4. place records into CHUNK-LOCAL segments (perfect write merge) ----------
// bkt[k*CHUNK_E + off] = (src << 6) | (dst & 63), region-sorted within the chunk.
__global__ __launch_bounds__(256) void k_place(const int4* __restrict__ dst4,
                                               const int4* __restrict__ src4,
                                               const uint* __restrict__ bh,
                                               uint* __restrict__ bkt) {
    __shared__ uint loff[NREG];
    int t = threadIdx.x;
    for (int b = t; b < NREG; b += 256) loff[b] = bh[blockIdx.x * NREG + b];
    __syncthreads();
    int base = blockIdx.x * CHUNK_U;
    uint kbase = (uint)blockIdx.x * CHUNK_E;
    for (int i = t; i < CHUNK_U; i += 256) {
        int u = base + i;
        if (u < N_UNITS) {
            int4 d = dst4[u];
            int4 s = src4[u];
            uint p0 = atomicAdd(&loff[d.x >> 6], 1u);
            uint p1 = atomicAdd(&loff[d.y >> 6], 1u);
            uint p2 = atomicAdd(&loff[d.z >> 6], 1u);
            uint p3 = atomicAdd(&loff[d.w >> 6], 1u);
            bkt[kbase + p0] = ((uint)s.x << 6) | ((uint)d.x & 63u);
            bkt[kbase + p1] = ((uint)s.y << 6) | ((uint)d.y & 63u);
            bkt[kbase + p2] = ((uint)s.z << 6) | ((uint)d.z & 63u);
            bkt[kbase + p3] = ((uint)s.w << 6) | ((uint)d.w & 63u);
        }
    }
}

// ---------- 5. finalize CSR per region: gather 367 mini-runs via LDS, rank, emit ----------
__global__ __launch_bounds__(256) void k_finalize(const uint* __restrict__ bkt,
                                                  const uint* __restrict__ bh,
                                                  const uint* __restrict__ rowtot,
                                                  const int* __restrict__ binPtr,
                                                  const float* __restrict__ sd,
                                                  int* __restrict__ rowptr,
                                                  int2* __restrict__ srcw) {
    __shared__ uint recs[REC_MAX];
    __shared__ uint part[256];
    __shared__ uint cnt64[64];
    __shared__ uint off64[64];
    int r = blockIdx.x;
    int t = threadIdx.x;
    int rbase = binPtr[r];
    int rcnt  = binPtr[r + 1] - rbase;

    // each thread owns chunks k0=2t, k1=2t+1
    int k0 = 2 * t, k1 = 2 * t + 1;
    uint s0 = 0, c0 = 0, s1 = 0, c1 = 0;
    if (k0 < NCB) {
        s0 = bh[k0 * NREG + r];
        uint e0 = (r + 1 < NREG) ? bh[k0 * NREG + r + 1] : rowtot[k0];
        c0 = e0 - s0;
    }
    if (k1 < NCB) {
        s1 = bh[k1 * NREG + r];
        uint e1 = (r + 1 < NREG) ? bh[k1 * NREG + r + 1] : rowtot[k1];
        c1 = e1 - s1;
    }
    uint own = c0 + c1;
    part[t] = own;
    __syncthreads();
    for (int off = 1; off < 256; off <<= 1) {
        uint v = (t >= off) ? part[t - off] : 0;
        __syncthreads();
        part[t] += v;
        __syncthreads();
    }
    uint w0 = part[t] - own;
    uint w1 = w0 + c0;
    for (uint i = 0; i < c0; ++i) recs[w0 + i] = bkt[(uint)k0 * CHUNK_E + s0 + i];
    for (uint i = 0; i < c1; ++i) recs[w1 + i] = bkt[(uint)k1 * CHUNK_E + s1 + i];
    if (t < 64) cnt64[t] = 0;
    __syncthreads();

    // local histogram over 64 nodes
    for (int e = t; e < rcnt; e += 256) atomicAdd(&cnt64[recs[e] & 63u], 1u);
    __syncthreads();
    if (t == 0) {
        uint run = 0;
        for (int i = 0; i < 64; ++i) { off64[i] = run; run += cnt64[i]; }
    }
    __syncthreads();
    int nbase = r * 64;
    int nloc = N_NODES - nbase; if (nloc > 64) nloc = 64;
    if (t < nloc) rowptr[nbase + t] = rbase + (int)off64[t];
    if (t < 64) cnt64[t] = 0;
    __syncthreads();

    // emit CSR records with weights
    for (int e = t; e < rcnt; e += 256) {
        uint rec = recs[e];
        uint loc = rec & 63u;
        uint s   = rec >> 6;
        uint pos = (uint)rbase + off64[loc] + atomicAdd(&cnt64[loc], 1u);
        float w = sd[s] * sd[nbase + (int)loc];
        srcw[pos] = make_int2((int)s, __float_as_int(w));
    }
}

// ---------- layer: wave-per-node gather over bf16 rows ----------
__global__ __launch_bounds__(256) void k_layer(const uint4* __restrict__ xb,
                                               const int* __restrict__ rowptr,
                                               const int2* __restrict__ srcw,
                                               uint4* __restrict__ aggb) {
    int wid = (blockIdx.x * blockDim.x + threadIdx.x) >> 6;
    if (wid >= N_NODES) return;                 // wave-uniform exit
    int lane = threadIdx.x & 63;
    int ep = lane >> 3;     // edge slot 0..7
    int j  = lane & 7;      // 16B chunk (dims j*8 .. j*8+7)

    int start = rowptr[wid];
    int end   = (wid + 1 < N_NODES) ? rowptr[wid + 1] : N_EDGES;

    float a0 = 0.f, a1 = 0.f, a2 = 0.f, a3 = 0.f;
    float a4 = 0.f, a5 = 0.f, a6 = 0.f, a7 = 0.f;
    for (int base = start; base < end; base += 8) {
        int ee = base + ep;
        if (ee < end) {
            int2 sw = srcw[ee];
            float w = __int_as_float(sw.y);
            uint4 v = xb[(size_t)sw.x * 8 + j];
            FMA2(v.x, a0, a1);
            FMA2(v.y, a2, a3);
            FMA2(v.z, a4, a5);
            FMA2(v.w, a6, a7);
        }
    }
    #pragma unroll
    for (int m = 8; m <= 32; m <<= 1) {
        a0 += __shfl_xor(a0, m, 64);
        a1 += __shfl_xor(a1, m, 64);
        a2 += __shfl_xor(a2, m, 64);
        a3 += __shfl_xor(a3, m, 64);
        a4 += __shfl_xor(a4, m, 64);
        a5 += __shfl_xor(a5, m, 64);
        a6 += __shfl_xor(a6, m, 64);
        a7 += __shfl_xor(a7, m, 64);
    }
    if (ep == 0) {
        uint4 r;
        r.x = pack2_bf16(a0, a1);
        r.y = pack2_bf16(a2, a3);
        r.z = pack2_bf16(a4, a5);
        r.w = pack2_bf16(a6, a7);
        aggb[(size_t)wid * 8 + j] = r;
    }
}

// ---------- final: out = 0.25*(emb + a1 + a2 + a3) ----------
__global__ void k_combine(const float4* __restrict__ emb,
                          const uint2* __restrict__ b1,
                          const uint2* __restrict__ b2,
                          const uint2* __restrict__ b3,
                          float4* __restrict__ out, int n4) {
    int i = blockIdx.x * blockDim.x + threadIdx.x;
    if (i >= n4) return;
    float4 e = emb[i];
    uint2 u1 = b1[i], u2 = b2[i], u3 = b3[i];
    float4 o;
    o.x = e.x + __uint_as_float(u1.x << 16)         + __uint_as_float(u2.x << 16)         + __uint_as_float(u3.x << 16);
    o.y = e.y + __uint_as_float(u1.x & 0xffff0000u) + __uint_as_float(u2.x & 0xffff0000u) + __uint_as_float(u3.x & 0xffff0000u);
    o.z = e.z + __uint_as_float(u1.y << 16)         + __uint_as_float(u2.y << 16)         + __uint_as_float(u3.y << 16);
    o.w = e.w + __uint_as_float(u1.y & 0xffff0000u) + __uint_as_float(u2.y & 0xffff0000u) + __uint_as_float(u3.y & 0xffff0000u);
    o.x *= 0.25f; o.y *= 0.25f; o.z *= 0.25f; o.w *= 0.25f;
    out[i] = o;
}

extern "C" void kernel_launch(void* const* d_in, const int* in_sizes, int n_in,
                              void* d_out, int out_size, void* d_ws, size_t ws_size,
                              hipStream_t stream) {
    const float* emb = (const float*)d_in[0];
    const float* sd  = (const float*)d_in[1];
    const int*   src = (const int*)d_in[2];
    const int*   dst = (const int*)d_in[3];
    float*       out = (float*)d_out;

    char* ws = (char*)d_ws;
    auto align256 = [](size_t x) { return (x + 255) & ~(size_t)255; };
    size_t off = 0;
    int*  rowptr = (int*)(ws + off);  off += align256((size_t)N_NODES * 4);
    uint* bh     = (uint*)(ws + off); off += align256((size_t)NCB * NREG * 4);    // 3.44 MB
    uint* rowtot = (uint*)(ws + off); off += align256((size_t)NCB * 4);
    uint* tot    = (uint*)(ws + off); off += align256((size_t)NREG * 4);
    int*  binPtr = (int*)(ws + off);  off += align256((size_t)(NREG + 1) * 4);
    uint* bkt    = (uint*)(ws + off); off += align256((size_t)NCB * CHUNK_E * 4); // 12.03 MB
    int2* srcw   = (int2*)(ws + off); off += align256((size_t)N_EDGES * 8);       // 24 MB
    const size_t rowBytes = (size_t)N_NODES * EMBED_DIM * 2;                      // 19.2 MB
    uint* buf0 = (uint*)(ws + off);   off += align256(rowBytes);  // xb0, then ag3
    uint* buf1 = (uint*)(ws + off);   off += align256(rowBytes);  // ag1
    uint* buf2 = (uint*)(ws + off);                                // ag2

    const int n4 = N_NODES * EMBED_DIM / 4;
    const int nblk4 = (n4 + 255) / 256;
    const int regblk = (NREG + 255) / 256;    // 10

    // ---- CSR build: chunk-local buckets, zero global returning atomics ----
    k_count<<<NCB, 256, 0, stream>>>((const int4*)dst, bh, rowtot);
    k_cols<<<regblk, 256, 0, stream>>>(bh, rowtot, tot);
    k_scan_small<<<1, 1024, 0, stream>>>(tot, binPtr);
    k_place<<<NCB, 256, 0, stream>>>((const int4*)dst, (const int4*)src, bh, bkt);
    k_finalize<<<NREG, 256, 0, stream>>>(bkt, bh, rowtot, binPtr, sd, rowptr, srcw);

    // ---- emb -> bf16 ----
    k_to_bf16<<<nblk4, 256, 0, stream>>>((const float4*)emb, (uint2*)buf0, n4);

    // ---- 3 layers, gather-only, bf16 in/out (buf0->buf1->buf2->buf0) ----
    const int lblk = (N_NODES + 3) / 4;
    k_layer<<<lblk, 256, 0, stream>>>((const uint4*)buf0, rowptr, srcw, (uint4*)buf1);
    k_layer<<<lblk, 256, 0, stream>>>((const uint4*)buf1, rowptr, srcw, (uint4*)buf2);
    k_layer<<<lblk, 256, 0, stream>>>((const uint4*)buf2, rowptr, srcw, (uint4*)buf0);

    // ---- combine ----
    k_combine<<<nblk4, 256, 0, stream>>>((const float4*)emb, (const uint2*)buf1,
                                         (const uint2*)buf2, (const uint2*)buf0,
                                         (float4*)out, n4);
}

// Round 8
// 311.238 us; speedup vs baseline: 1.1807x; 1.1807x over previous
//
#include <hip/hip_runtime.h>

#define N_NODES   150000
#define N_EDGES   3000000
#define EMBED_DIM 64
#define N_UNITS   (N_EDGES / 4)                         // 750000 int4 units
#define NREG      2344                                  // regions of 64 nodes
#define CHUNK_U   2048                                  // int4 units per chunk
#define CHUNK_E   (CHUNK_U * 4)                         // 8192 edges per chunk
#define NCB       ((N_UNITS + CHUNK_U - 1) / CHUNK_U)   // 367 chunks
#define REC_MAX   2560                                  // region staging (avg 1280)
#define KGRP      8                                     // k-parallel groups in cols
#define KPER      ((NCB + KGRP - 1) / KGRP)             // 46

typedef unsigned int uint;

// ---- bf16 helpers (RNE pack, shift unpack) ----
__device__ inline uint pack2_bf16(float a, float b) {
    uint ua = __float_as_uint(a);
    uint ub = __float_as_uint(b);
    ua += 0x7fffu + ((ua >> 16) & 1u);
    ub += 0x7fffu + ((ub >> 16) & 1u);
    return (ua >> 16) | (ub & 0xffff0000u);
}
#define FMA2(u, A0, A1)                                        \
    {   float _lo = __uint_as_float((u) << 16);                \
        float _hi = __uint_as_float((u) & 0xffff0000u);        \
        (A0) += w * _lo;  (A1) += w * _hi; }

// ---------- fp32 -> bf16 convert ----------
__global__ void k_to_bf16(const float4* __restrict__ in, uint2* __restrict__ out, int n4) {
    int i = blockIdx.x * blockDim.x + threadIdx.x;
    if (i < n4) {
        float4 v = in[i];
        out[i] = make_uint2(pack2_bf16(v.x, v.y), pack2_bf16(v.z, v.w));
    }
}

// ---------- 1. FUSED: per-chunk hist -> LDS scan -> place into chunk-local bkt ----------
// bh[k][b] = exclusive offset of region b within chunk k (written for finalize).
// rowtot[k] = edges in chunk k. bkt[k*CHUNK_E + off] = (src<<6) | (dst&63).
__global__ __launch_bounds__(256) void k_count_place(const int4* __restrict__ dst4,
                                                     const int4* __restrict__ src4,
                                                     uint* __restrict__ bh,
                                                     uint* __restrict__ rowtot,
                                                     uint* __restrict__ bkt) {
    __shared__ uint cnt[NREG];
    __shared__ uint part[256];
    int t = threadIdx.x;
    for (int b = t; b < NREG; b += 256) cnt[b] = 0;
    __syncthreads();
    int base = blockIdx.x * CHUNK_U;
    for (int i = t; i < CHUNK_U; i += 256) {
        int u = base + i;
        if (u < N_UNITS) {
            int4 d = dst4[u];
            atomicAdd(&cnt[d.x >> 6], 1u);
            atomicAdd(&cnt[d.y >> 6], 1u);
            atomicAdd(&cnt[d.z >> 6], 1u);
            atomicAdd(&cnt[d.w >> 6], 1u);
        }
    }
    __syncthreads();
    // exclusive scan of cnt[0..NREG) in place
    const int CPT = (NREG + 255) / 256;     // 10
    int b0 = t * CPT, b1 = b0 + CPT; if (b1 > NREG) b1 = NREG; if (b0 > NREG) b0 = NREG;
    uint own = 0;
    for (int b = b0; b < b1; ++b) own += cnt[b];
    part[t] = own;
    __syncthreads();
    for (int off = 1; off < 256; off <<= 1) {
        uint v = (t >= off) ? part[t - off] : 0;
        __syncthreads();
        part[t] += v;
        __syncthreads();
    }
    uint run = part[t] - own;
    for (int b = b0; b < b1; ++b) { uint c = cnt[b]; cnt[b] = run; run += c; }
    __syncthreads();
    // persist offsets for finalize
    for (int b = t; b < NREG; b += 256) bh[blockIdx.x * NREG + b] = cnt[b];
    if (t == 255) rowtot[blockIdx.x] = part[255];
    __syncthreads();
    // place records using the same LDS offsets (mutating cnt)
    uint kbase = (uint)blockIdx.x * CHUNK_E;
    for (int i = t; i < CHUNK_U; i += 256) {
        int u = base + i;
        if (u < N_UNITS) {
            int4 d = dst4[u];
            int4 s = src4[u];
            uint p0 = atomicAdd(&cnt[d.x >> 6], 1u);
            uint p1 = atomicAdd(&cnt[d.y >> 6], 1u);
            uint p2 = atomicAdd(&cnt[d.z >> 6], 1u);
            uint p3 = atomicAdd(&cnt[d.w >> 6], 1u);
            bkt[kbase + p0] = ((uint)s.x << 6) | ((uint)d.x & 63u);
            bkt[kbase + p1] = ((uint)s.y << 6) | ((uint)d.y & 63u);
            bkt[kbase + p2] = ((uint)s.z << 6) | ((uint)d.z & 63u);
            bkt[kbase + p3] = ((uint)s.w << 6) | ((uint)d.w & 63u);
        }
    }
}

// ---------- 2. region partial totals, 8-way k-parallel ----------
__global__ void k_cols(const uint* __restrict__ bh, const uint* __restrict__ rowtot,
                       uint* __restrict__ partial) {
    int tid = blockIdx.x * blockDim.x + threadIdx.x;
    if (tid >= KGRP * NREG) return;
    int g = tid / NREG;
    int r = tid % NREG;
    int kend = (g + 1) * KPER; if (kend > NCB) kend = NCB;
    uint run = 0;
    if (r + 1 < NREG) {
        for (int k = g * KPER; k < kend; ++k)
            run += bh[k * NREG + r + 1] - bh[k * NREG + r];
    } else {
        for (int k = g * KPER; k < kend; ++k)
            run += rowtot[k] - bh[k * NREG + r];
    }
    partial[g * NREG + r] = run;
}

// ---------- 3. exclusive scan of region totals -> binPtr[0..NREG] ----------
__global__ void k_scan_small(const uint* __restrict__ partial, int* __restrict__ binPtr) {
    __shared__ uint s[1024];
    int t = threadIdx.x;
    int base = t * 3;
    uint v0 = 0, v1 = 0, v2 = 0;
    #pragma unroll
    for (int g = 0; g < KGRP; ++g) {
        if (base + 0 < NREG) v0 += partial[g * NREG + base + 0];
        if (base + 1 < NREG) v1 += partial[g * NREG + base + 1];
        if (base + 2 < NREG) v2 += partial[g * NREG + base + 2];
    }
    uint s3 = v0 + v1 + v2;
    s[t] = s3;
    __syncthreads();
    for (int off = 1; off < 1024; off <<= 1) {
        uint add = (t >= off) ? s[t - off] : 0;
        __syncthreads();
        s[t] += add;
        __syncthreads();
    }
    uint excl = s[t] - s3;
    if (base + 0 < NREG) binPtr[base + 0] = (int)excl;
    if (base + 1 < NREG) binPtr[base + 1] = (int)(excl + v0);
    if (base + 2 < NREG) binPtr[base + 2] = (int)(excl + v0 + v1);
    if (t == 1023) binPtr[NREG] = (int)s[1023];
}

// ---------- 4. finalize CSR per region ----------
__global__ __launch_bounds__(256) void k_finalize(const uint* __restrict__ bkt,
                                                  const uint* __restrict__ bh,
                                                  const uint* __restrict__ rowtot,
                                                  const int* __restrict__ binPtr,
                                                  const float* __restrict__ sd,
                                                  int* __restrict__ rowptr,
                                                  int2* __restrict__ srcw) {
    __shared__ uint recs[REC_MAX];
    __shared__ uint part[256];
    __shared__ uint cnt64[64];
    __shared__ uint off64[64];
    int r = blockIdx.x;
    int t = threadIdx.x;
    int rbase = binPtr[r];
    int rcnt  = binPtr[r + 1] - rbase;

    int k0 = 2 * t, k1 = 2 * t + 1;
    uint s0 = 0, c0 = 0, s1 = 0, c1 = 0;
    if (k0 < NCB) {
        s0 = bh[k0 * NREG + r];
        uint e0 = (r + 1 < NREG) ? bh[k0 * NREG + r + 1] : rowtot[k0];
        c0 = e0 - s0;
    }
    if (k1 < NCB) {
        s1 = bh[k1 * NREG + r];
        uint e1 = (r + 1 < NREG) ? bh[k1 * NREG + r + 1] : rowtot[k1];
        c1 = e1 - s1;
    }
    uint own = c0 + c1;
    part[t] = own;
    __syncthreads();
    for (int off = 1; off < 256; off <<= 1) {
        uint v = (t >= off) ? part[t - off] : 0;
        __syncthreads();
        part[t] += v;
        __syncthreads();
    }
    uint w0 = part[t] - own;
    uint w1 = w0 + c0;
    for (uint i = 0; i < c0; ++i) recs[w0 + i] = bkt[(uint)k0 * CHUNK_E + s0 + i];
    for (uint i = 0; i < c1; ++i) recs[w1 + i] = bkt[(uint)k1 * CHUNK_E + s1 + i];
    if (t < 64) cnt64[t] = 0;
    __syncthreads();

    for (int e = t; e < rcnt; e += 256) atomicAdd(&cnt64[recs[e] & 63u], 1u);
    __syncthreads();
    if (t == 0) {
        uint run = 0;
        for (int i = 0; i < 64; ++i) { off64[i] = run; run += cnt64[i]; }
    }
    __syncthreads();
    int nbase = r * 64;
    int nloc = N_NODES - nbase; if (nloc > 64) nloc = 64;
    if (t < nloc) rowptr[nbase + t] = rbase + (int)off64[t];
    if (t < 64) cnt64[t] = 0;
    __syncthreads();

    for (int e = t; e < rcnt; e += 256) {
        uint rec = recs[e];
        uint loc = rec & 63u;
        uint s   = rec >> 6;
        uint pos = (uint)rbase + off64[loc] + atomicAdd(&cnt64[loc], 1u);
        float w = sd[s] * sd[nbase + (int)loc];
        srcw[pos] = make_int2((int)s, __float_as_int(w));
    }
}

// ---------- layer: wave-per-node gather, branch-free inner loop ----------
__global__ __launch_bounds__(256) void k_layer(const uint4* __restrict__ xb,
                                               const int* __restrict__ rowptr,
                                               const int2* __restrict__ srcw,
                                               uint4* __restrict__ aggb) {
    int wid = (blockIdx.x * blockDim.x + threadIdx.x) >> 6;
    if (wid >= N_NODES) return;                 // wave-uniform exit
    int lane = threadIdx.x & 63;
    int ep = lane >> 3;     // edge slot 0..7
    int j  = lane & 7;      // 16B chunk (dims j*8 .. j*8+7)
    uint joff = (uint)j << 4;

    int start = rowptr[wid];
    int end   = (wid + 1 < N_NODES) ? rowptr[wid + 1] : N_EDGES;
    int endm1 = end - 1;

    float a0 = 0.f, a1 = 0.f, a2 = 0.f, a3 = 0.f;
    float a4 = 0.f, a5 = 0.f, a6 = 0.f, a7 = 0.f;
    #pragma unroll 2
    for (int base = start; base < end; base += 8) {
        int ee  = base + ep;
        int eec = min(ee, endm1);
        int2 sw = srcw[eec];                                   // unconditional
        float w = (ee < end) ? __int_as_float(sw.y) : 0.0f;    // one cndmask
        uint4 v = *(const uint4*)((const char*)xb + (((uint)sw.x << 7) + joff));
        FMA2(v.x, a0, a1);
        FMA2(v.y, a2, a3);
        FMA2(v.z, a4, a5);
        FMA2(v.w, a6, a7);
    }
    #pragma unroll
    for (int m = 8; m <= 32; m <<= 1) {
        a0 += __shfl_xor(a0, m, 64);
        a1 += __shfl_xor(a1, m, 64);
        a2 += __shfl_xor(a2, m, 64);
        a3 += __shfl_xor(a3, m, 64);
        a4 += __shfl_xor(a4, m, 64);
        a5 += __shfl_xor(a5, m, 64);
        a6 += __shfl_xor(a6, m, 64);
        a7 += __shfl_xor(a7, m, 64);
    }
    if (ep == 0) {
        uint4 r;
        r.x = pack2_bf16(a0, a1);
        r.y = pack2_bf16(a2, a3);
        r.z = pack2_bf16(a4, a5);
        r.w = pack2_bf16(a6, a7);
        aggb[(size_t)wid * 8 + j] = r;
    }
}

// ---------- final: out = 0.25*(emb + a1 + a2 + a3) ----------
__global__ void k_combine(const float4* __restrict__ emb,
                          const uint2* __restrict__ b1,
                          const uint2* __restrict__ b2,
                          const uint2* __restrict__ b3,
                          float4* __restrict__ out, int n4) {
    int i = blockIdx.x * blockDim.x + threadIdx.x;
    if (i >= n4) return;
    float4 e = emb[i];
    uint2 u1 = b1[i], u2 = b2[i], u3 = b3[i];
    float4 o;
    o.x = e.x + __uint_as_float(u1.x << 16)         + __uint_as_float(u2.x << 16)         + __uint_as_float(u3.x << 16);
    o.y = e.y + __uint_as_float(u1.x & 0xffff0000u) + __uint_as_float(u2.x & 0xffff0000u) + __uint_as_float(u3.x & 0xffff0000u);
    o.z = e.z + __uint_as_float(u1.y << 16)         + __uint_as_float(u2.y << 16)         + __uint_as_float(u3.y << 16);
    o.w = e.w + __uint_as_float(u1.y & 0xffff0000u) + __uint_as_float(u2.y & 0xffff0000u) + __uint_as_float(u3.y & 0xffff0000u);
    o.x *= 0.25f; o.y *= 0.25f; o.z *= 0.25f; o.w *= 0.25f;
    out[i] = o;
}

extern "C" void kernel_launch(void* const* d_in, const int* in_sizes, int n_in,
                              void* d_out, int out_size, void* d_ws, size_t ws_size,
                              hipStream_t stream) {
    const float* emb = (const float*)d_in[0];
    const float* sd  = (const float*)d_in[1];
    const int*   src = (const int*)d_in[2];
    const int*   dst = (const int*)d_in[3];
    float*       out = (float*)d_out;

    char* ws = (char*)d_ws;
    auto align256 = [](size_t x) { return (x + 255) & ~(size_t)255; };
    size_t off = 0;
    int*  rowptr  = (int*)(ws + off);  off += align256((size_t)N_NODES * 4);
    uint* bh      = (uint*)(ws + off); off += align256((size_t)NCB * NREG * 4);    // 3.44 MB
    uint* rowtot  = (uint*)(ws + off); off += align256((size_t)NCB * 4);
    uint* partial = (uint*)(ws + off); off += align256((size_t)KGRP * NREG * 4);   // 75 KB
    int*  binPtr  = (int*)(ws + off);  off += align256((size_t)(NREG + 1) * 4);
    uint* bkt     = (uint*)(ws + off); off += align256((size_t)NCB * CHUNK_E * 4); // 12.03 MB
    int2* srcw    = (int2*)(ws + off); off += align256((size_t)N_EDGES * 8);       // 24 MB
    const size_t rowBytes = (size_t)N_NODES * EMBED_DIM * 2;                       // 19.2 MB
    uint* buf0 = (uint*)(ws + off);    off += align256(rowBytes);  // xb0, then ag3
    uint* buf1 = (uint*)(ws + off);    off += align256(rowBytes);  // ag1
    uint* buf2 = (uint*)(ws + off);                                 // ag2

    const int n4 = N_NODES * EMBED_DIM / 4;
    const int nblk4 = (n4 + 255) / 256;
    const int colsblk = (KGRP * NREG + 255) / 256;   // 74

    // ---- CSR build: fused chunk-local bucketing, zero global returning atomics ----
    k_count_place<<<NCB, 256, 0, stream>>>((const int4*)dst, (const int4*)src,
                                           bh, rowtot, bkt);
    k_cols<<<colsblk, 256, 0, stream>>>(bh, rowtot, partial);
    k_scan_small<<<1, 1024, 0, stream>>>(partial, binPtr);
    k_finalize<<<NREG, 256, 0, stream>>>(bkt, bh, rowtot, binPtr, sd, rowptr, srcw);

    // ---- emb -> bf16 ----
    k_to_bf16<<<nblk4, 256, 0, stream>>>((const float4*)emb, (uint2*)buf0, n4);

    // ---- 3 layers, gather-only, bf16 in/out (buf0->buf1->buf2->buf0) ----
    const int lblk = (N_NODES + 3) / 4;
    k_layer<<<lblk, 256, 0, stream>>>((const uint4*)buf0, rowptr, srcw, (uint4*)buf1);
    k_layer<<<lblk, 256, 0, stream>>>((const uint4*)buf1, rowptr, srcw, (uint4*)buf2);
    k_layer<<<lblk, 256, 0, stream>>>((const uint4*)buf2, rowptr, srcw, (uint4*)buf0);

    // ---- combine ----
    k_combine<<<nblk4, 256, 0, stream>>>((const float4*)emb, (const uint2*)buf1,
                                         (const uint2*)buf2, (const uint2*)buf0,
                                         (float4*)out, n4);
}